// Round 3
// baseline (1990.764 us; speedup 1.0000x reference)
//
#include <hip/hip_runtime.h>
#include <hip/hip_bf16.h>

// Problem constants (from reference)
#define NP     100000   // papers (receivers)
#define NA     50000    // authors
#define DIM    128      // feature dim
#define UNITS  128      // output units
#define NEDGE  500000   // edges per edge set

#define GEMM_ROWS 32    // rows of X per block in the GEMM kernel
#define GP ((NP + GEMM_ROWS - 1) / GEMM_ROWS)   // 3125
#define GA ((NA + GEMM_ROWS - 1) / GEMM_ROWS)   // 1563

// ---------------------------------------------------------------------------
// Fused f32 GEMM over all three transforms:
//   blocks [0, GP)            : H_c   = x_paper  @ W_cites
//   blocks [GP, GP+GA)        : H_w   = x_author @ W_writes
//   blocks [GP+GA, 2*GP+GA)   : accum = x_paper  @ W_self   (+ deg := 1.0)
// Per block: W fully in LDS (64 KB), 32-row X tile in LDS (16 KB) -> 2 blk/CU.
// 256 threads, each computes a 4x4 register tile.
// ---------------------------------------------------------------------------
__global__ __launch_bounds__(256, 2) void gemm_all(
    const float* __restrict__ x_paper, const float* __restrict__ x_author,
    const float* __restrict__ W_cites, const float* __restrict__ W_writes,
    const float* __restrict__ W_self,
    float* __restrict__ H_c, float* __restrict__ H_w,
    float* __restrict__ accum, float* __restrict__ deg)
{
    // Uniform (per-block) problem select.
    const float* X; const float* W; float* H; float* dg; int nrows; int bb;
    if (blockIdx.x < GP) {
        X = x_paper;  W = W_cites;  H = H_c;   dg = nullptr; nrows = NP; bb = blockIdx.x;
    } else if (blockIdx.x < GP + GA) {
        X = x_author; W = W_writes; H = H_w;   dg = nullptr; nrows = NA; bb = blockIdx.x - GP;
    } else {
        X = x_paper;  W = W_self;   H = accum; dg = deg;     nrows = NP; bb = blockIdx.x - GP - GA;
    }

    __shared__ float Wl[DIM * UNITS];       // 64 KB
    __shared__ float Xl[GEMM_ROWS * DIM];   // 16 KB

    const int tid  = threadIdx.x;
    const int row0 = bb * GEMM_ROWS;

    // Stage W: 4096 float4 / 256 threads = 16 each, coalesced.
    const float4* W4  = (const float4*)W;
    float4*       Wl4 = (float4*)Wl;
#pragma unroll
    for (int i = 0; i < 16; ++i)
        Wl4[i * 256 + tid] = W4[i * 256 + tid];

    // Stage X tile: 1024 float4 / 256 threads = 4 each, guarded for tail.
    const float4* X4  = (const float4*)(X + (size_t)row0 * DIM);
    float4*       Xl4 = (float4*)Xl;
#pragma unroll
    for (int i = 0; i < 4; ++i) {
        int idx = i * 256 + tid;            // float4 index; row = idx/32
        if (row0 + (idx >> 5) < nrows)
            Xl4[idx] = X4[idx];
    }
    __syncthreads();

    // Thread tile: rg in [0,8) picks 4 rows, ug in [0,32) picks 4 units.
    const int ug = tid & 31;
    const int rg = tid >> 5;
    const int r0 = rg * 4;

    float acc[4][4];
#pragma unroll
    for (int r = 0; r < 4; ++r)
#pragma unroll
        for (int j = 0; j < 4; ++j) acc[r][j] = 0.0f;

#pragma unroll 4
    for (int kk = 0; kk < 32; ++kk) {       // k0 = 4*kk
        float4 xv[4], wv[4];
#pragma unroll
        for (int r = 0; r < 4; ++r) xv[r] = Xl4[(r0 + r) * 32 + kk];       // wave-broadcast
#pragma unroll
        for (int i = 0; i < 4; ++i) wv[i] = Wl4[(kk * 4 + i) * 32 + ug];   // linear, conflict-free b128
#pragma unroll
        for (int r = 0; r < 4; ++r) {
            const float xr0 = xv[r].x, xr1 = xv[r].y, xr2 = xv[r].z, xr3 = xv[r].w;
            acc[r][0] = fmaf(xr0, wv[0].x, acc[r][0]);
            acc[r][1] = fmaf(xr0, wv[0].y, acc[r][1]);
            acc[r][2] = fmaf(xr0, wv[0].z, acc[r][2]);
            acc[r][3] = fmaf(xr0, wv[0].w, acc[r][3]);
            acc[r][0] = fmaf(xr1, wv[1].x, acc[r][0]);
            acc[r][1] = fmaf(xr1, wv[1].y, acc[r][1]);
            acc[r][2] = fmaf(xr1, wv[1].z, acc[r][2]);
            acc[r][3] = fmaf(xr1, wv[1].w, acc[r][3]);
            acc[r][0] = fmaf(xr2, wv[2].x, acc[r][0]);
            acc[r][1] = fmaf(xr2, wv[2].y, acc[r][1]);
            acc[r][2] = fmaf(xr2, wv[2].z, acc[r][2]);
            acc[r][3] = fmaf(xr2, wv[2].w, acc[r][3]);
            acc[r][0] = fmaf(xr3, wv[3].x, acc[r][0]);
            acc[r][1] = fmaf(xr3, wv[3].y, acc[r][1]);
            acc[r][2] = fmaf(xr3, wv[3].z, acc[r][2]);
            acc[r][3] = fmaf(xr3, wv[3].w, acc[r][3]);
        }
    }

    // Store 4 rows x 1 float4 each.
    float4* H4 = (float4*)H;
#pragma unroll
    for (int r = 0; r < 4; ++r) {
        int row = row0 + r0 + r;
        if (row < nrows) {
            float4 v; v.x = acc[r][0]; v.y = acc[r][1]; v.z = acc[r][2]; v.w = acc[r][3];
            H4[(size_t)row * 32 + ug] = v;
        }
    }

    // Self-loop degree init (only for the W_self problem).
    if (dg != nullptr && tid < GEMM_ROWS && (row0 + tid) < nrows)
        dg[row0 + tid] = 1.0f;
}

// ---------------------------------------------------------------------------
// Fused edge scatter over both edge sets:
//   blocks [0, EB)     : accum[cites_dst]  += H_c[cites_src];  deg += 1
//   blocks [EB, 2*EB)  : accum[writes_dst] += H_w[writes_src]; deg += 1
// 32 lanes per edge, float4 gather (512 B contiguous), 4 f32 atomics per lane.
// unsafeAtomicAdd guarantees the HW global_atomic_add_f32 (no CAS loop);
// denormal-flush semantics are irrelevant at these magnitudes.
// ---------------------------------------------------------------------------
#define EB ((NEDGE * 32 + 255) / 256)   // 62500 blocks per edge set

__global__ __launch_bounds__(256) void edge_scatter_all(
    const float* __restrict__ H_c, const int* __restrict__ c_src,
    const int* __restrict__ c_dst,
    const float* __restrict__ H_w, const int* __restrict__ w_src,
    const int* __restrict__ w_dst,
    float* __restrict__ accum, float* __restrict__ deg)
{
    const float* H; const int* src; const int* dst; int b;
    if (blockIdx.x < EB) { H = H_c; src = c_src; dst = c_dst; b = blockIdx.x; }
    else                 { H = H_w; src = w_src; dst = w_dst; b = blockIdx.x - EB; }

    const int g = b * blockDim.x + threadIdx.x;
    const int e = g >> 5;
    if (e >= NEDGE) return;
    const int l = g & 31;

    const int s = src[e];
    const int d = dst[e];

    const float4 v = ((const float4*)(H + (size_t)s * UNITS))[l];
    float* a = accum + (size_t)d * UNITS + l * 4;
    unsafeAtomicAdd(a + 0, v.x);
    unsafeAtomicAdd(a + 1, v.y);
    unsafeAtomicAdd(a + 2, v.z);
    unsafeAtomicAdd(a + 3, v.w);
    if (l == 0) unsafeAtomicAdd(deg + d, 1.0f);
}

// ---------------------------------------------------------------------------
// Finalize: out = relu(accum / deg + bias).  deg >= 1 always (self-loop).
// ---------------------------------------------------------------------------
__global__ __launch_bounds__(256) void finalize(
    const float* __restrict__ accum, const float* __restrict__ deg,
    const float* __restrict__ bias, float* __restrict__ out, int nrows)
{
    const int idx = blockIdx.x * blockDim.x + threadIdx.x;  // float4 index
    const int total = nrows * (UNITS / 4);
    if (idx >= total) return;
    const int row = idx >> 5;
    const int c4  = idx & 31;

    const float inv = 1.0f / deg[row];
    float4 a = ((const float4*)accum)[idx];
    float4 b = ((const float4*)bias)[c4];
    float4 o;
    o.x = fmaxf(fmaf(a.x, inv, b.x), 0.0f);
    o.y = fmaxf(fmaf(a.y, inv, b.y), 0.0f);
    o.z = fmaxf(fmaf(a.z, inv, b.z), 0.0f);
    o.w = fmaxf(fmaf(a.w, inv, b.w), 0.0f);
    ((float4*)out)[idx] = o;
}

// ---------------------------------------------------------------------------
extern "C" void kernel_launch(void* const* d_in, const int* in_sizes, int n_in,
                              void* d_out, int out_size, void* d_ws, size_t ws_size,
                              hipStream_t stream)
{
    const float* x_paper    = (const float*)d_in[0];
    const float* x_author   = (const float*)d_in[1];
    const float* W_cites    = (const float*)d_in[2];
    const float* W_writes   = (const float*)d_in[3];
    const float* W_self     = (const float*)d_in[4];
    const float* bias       = (const float*)d_in[5];
    const int*   cites_src  = (const int*)d_in[6];
    const int*   cites_dst  = (const int*)d_in[7];
    const int*   writes_src = (const int*)d_in[8];
    const int*   writes_dst = (const int*)d_in[9];
    float* out = (float*)d_out;

    // Workspace layout (all f32):
    //   H_c   : NP*128  (51.2 MB)
    //   H_w   : NA*128  (25.6 MB)
    //   accum : NP*128  (51.2 MB)   -- initialized by the W_self GEMM part
    //   deg   : NP      (0.4 MB)    -- initialized to 1.0 by the W_self GEMM part
    char* ws = (char*)d_ws;
    float* H_c   = (float*)(ws);
    float* H_w   = (float*)(ws + ((size_t)NP * UNITS * 4));
    float* accum = (float*)(ws + ((size_t)NP * UNITS * 4) + ((size_t)NA * UNITS * 4));
    float* deg   = (float*)(ws + 2 * ((size_t)NP * UNITS * 4) + ((size_t)NA * UNITS * 4));

    // 1) All three transforms in one dispatch (tails overlap, 2 fewer launches).
    gemm_all<<<2 * GP + GA, 256, 0, stream>>>(
        x_paper, x_author, W_cites, W_writes, W_self, H_c, H_w, accum, deg);

    // 2) Both edge scatters in one dispatch.
    edge_scatter_all<<<2 * EB, 256, 0, stream>>>(
        H_c, cites_src, cites_dst, H_w, writes_src, writes_dst, accum, deg);

    // 3) Mean + bias + relu.
    const int ftotal = NP * (UNITS / 4);
    finalize<<<(ftotal + 255) / 256, 256, 0, stream>>>(accum, deg, bias, out, NP);
}

// Round 4
// 530.090 us; speedup vs baseline: 3.7555x; 3.7555x over previous
//
#include <hip/hip_runtime.h>
#include <hip/hip_bf16.h>

// Problem constants (from reference)
#define NP     100000   // papers (receivers)
#define NA     50000    // authors
#define DIM    128      // feature dim
#define UNITS  128      // output units
#define NEDGE  500000   // edges per edge set
#define NE2    (2 * NEDGE)

#define GEMM_ROWS 32
#define GP (NP / GEMM_ROWS)                       // 3125 (exact)
#define GA ((NA + GEMM_ROWS - 1) / GEMM_ROWS)     // 1563

#define CHUNK  1024
#define NCHUNK ((NP + CHUNK - 1) / CHUNK)         // 98

// ---------------------------------------------------------------------------
// Sender transforms (atomic-free): unified H buffer.
//   blocks [0, GP)       : H[0..NP)        = x_paper  @ W_cites
//   blocks [GP, GP+GA)   : H[NP..NP+NA)    = x_author @ W_writes
// W in LDS (64 KB) + 32-row X tile (16 KB) -> 2 blocks/CU. 4x4 reg tiles.
// ---------------------------------------------------------------------------
__global__ __launch_bounds__(256, 2) void gemm_all(
    const float* __restrict__ x_paper, const float* __restrict__ x_author,
    const float* __restrict__ W_cites, const float* __restrict__ W_writes,
    float* __restrict__ H)
{
    const float* X; const float* W; float* Ho; int nrows; int bb;
    if (blockIdx.x < GP) {
        X = x_paper;  W = W_cites;  Ho = H;                       nrows = NP; bb = blockIdx.x;
    } else {
        X = x_author; W = W_writes; Ho = H + (size_t)NP * UNITS;  nrows = NA; bb = blockIdx.x - GP;
    }

    __shared__ float Wl[DIM * UNITS];       // 64 KB
    __shared__ float Xl[GEMM_ROWS * DIM];   // 16 KB

    const int tid  = threadIdx.x;
    const int row0 = bb * GEMM_ROWS;

    const float4* W4  = (const float4*)W;
    float4*       Wl4 = (float4*)Wl;
#pragma unroll
    for (int i = 0; i < 16; ++i)
        Wl4[i * 256 + tid] = W4[i * 256 + tid];

    const float4* X4  = (const float4*)(X + (size_t)row0 * DIM);
    float4*       Xl4 = (float4*)Xl;
#pragma unroll
    for (int i = 0; i < 4; ++i) {
        int idx = i * 256 + tid;
        if (row0 + (idx >> 5) < nrows)
            Xl4[idx] = X4[idx];
    }
    __syncthreads();

    const int ug = tid & 31;
    const int rg = tid >> 5;
    const int r0 = rg * 4;

    float acc[4][4];
#pragma unroll
    for (int r = 0; r < 4; ++r)
#pragma unroll
        for (int j = 0; j < 4; ++j) acc[r][j] = 0.0f;

#pragma unroll 4
    for (int kk = 0; kk < 32; ++kk) {
        float4 xv[4], wv[4];
#pragma unroll
        for (int r = 0; r < 4; ++r) xv[r] = Xl4[(r0 + r) * 32 + kk];
#pragma unroll
        for (int i = 0; i < 4; ++i) wv[i] = Wl4[(kk * 4 + i) * 32 + ug];
#pragma unroll
        for (int r = 0; r < 4; ++r) {
            const float xr0 = xv[r].x, xr1 = xv[r].y, xr2 = xv[r].z, xr3 = xv[r].w;
            acc[r][0] = fmaf(xr0, wv[0].x, acc[r][0]);
            acc[r][1] = fmaf(xr0, wv[0].y, acc[r][1]);
            acc[r][2] = fmaf(xr0, wv[0].z, acc[r][2]);
            acc[r][3] = fmaf(xr0, wv[0].w, acc[r][3]);
            acc[r][0] = fmaf(xr1, wv[1].x, acc[r][0]);
            acc[r][1] = fmaf(xr1, wv[1].y, acc[r][1]);
            acc[r][2] = fmaf(xr1, wv[1].z, acc[r][2]);
            acc[r][3] = fmaf(xr1, wv[1].w, acc[r][3]);
            acc[r][0] = fmaf(xr2, wv[2].x, acc[r][0]);
            acc[r][1] = fmaf(xr2, wv[2].y, acc[r][1]);
            acc[r][2] = fmaf(xr2, wv[2].z, acc[r][2]);
            acc[r][3] = fmaf(xr2, wv[2].w, acc[r][3]);
            acc[r][0] = fmaf(xr3, wv[3].x, acc[r][0]);
            acc[r][1] = fmaf(xr3, wv[3].y, acc[r][1]);
            acc[r][2] = fmaf(xr3, wv[3].z, acc[r][2]);
            acc[r][3] = fmaf(xr3, wv[3].w, acc[r][3]);
        }
    }

    float4* H4 = (float4*)Ho;
#pragma unroll
    for (int r = 0; r < 4; ++r) {
        int row = row0 + r0 + r;
        if (row < nrows) {
            float4 v; v.x = acc[r][0]; v.y = acc[r][1]; v.z = acc[r][2]; v.w = acc[r][3];
            H4[(size_t)row * 32 + ug] = v;
        }
    }
}

// ---------------------------------------------------------------------------
// CSR build: zero -> hist -> scan(A,B,C) -> fill
// ---------------------------------------------------------------------------
__global__ __launch_bounds__(256) void zero_count(int* __restrict__ count)
{
    int i = blockIdx.x * 256 + threadIdx.x;
    if (i < NP) count[i] = 0;
}

__global__ __launch_bounds__(256) void hist_k(
    const int* __restrict__ c_dst, const int* __restrict__ w_dst,
    int* __restrict__ count)
{
    int i = blockIdx.x * 256 + threadIdx.x;
    if (i >= NE2) return;
    int d = (i < NEDGE) ? c_dst[i] : w_dst[i - NEDGE];
    atomicAdd(&count[d], 1);
}

// per-1024-chunk sums
__global__ __launch_bounds__(256) void scanA(
    const int* __restrict__ count, int* __restrict__ csum)
{
    __shared__ int red[256];
    const int c = blockIdx.x, t = threadIdx.x;
    const int base = c * CHUNK + t * 4;
    int s = 0;
#pragma unroll
    for (int r = 0; r < 4; ++r)
        if (base + r < NP) s += count[base + r];
    red[t] = s; __syncthreads();
#pragma unroll
    for (int off = 128; off > 0; off >>= 1) {
        if (t < off) red[t] += red[t + off];
        __syncthreads();
    }
    if (t == 0) csum[c] = red[0];
}

// exclusive scan of the NCHUNK chunk sums (NCHUNK <= 128)
__global__ __launch_bounds__(128) void scanB(
    const int* __restrict__ csum, int* __restrict__ coff)
{
    __shared__ int ts[128];
    const int t = threadIdx.x;
    const int v = (t < NCHUNK) ? csum[t] : 0;
    ts[t] = v; __syncthreads();
    for (int off = 1; off < 128; off <<= 1) {
        int x = (t >= off) ? ts[t - off] : 0;
        __syncthreads();
        ts[t] += x;
        __syncthreads();
    }
    if (t < NCHUNK) coff[t] = ts[t] - v;   // exclusive
}

// in-chunk exclusive scan -> cursor[] = segment starts
__global__ __launch_bounds__(256) void scanC(
    const int* __restrict__ count, const int* __restrict__ coff,
    int* __restrict__ cursor)
{
    __shared__ int ts[256];
    const int c = blockIdx.x, t = threadIdx.x;
    const int base = c * CHUNK + t * 4;
    int v0 = 0, v1 = 0, v2 = 0, v3 = 0;
    if (base + 0 < NP) v0 = count[base + 0];
    if (base + 1 < NP) v1 = count[base + 1];
    if (base + 2 < NP) v2 = count[base + 2];
    if (base + 3 < NP) v3 = count[base + 3];
    const int s = v0 + v1 + v2 + v3;
    ts[t] = s; __syncthreads();
    for (int off = 1; off < 256; off <<= 1) {
        int x = (t >= off) ? ts[t - off] : 0;
        __syncthreads();
        ts[t] += x;
        __syncthreads();
    }
    int excl = ts[t] - s + coff[c];
    if (base + 0 < NP) cursor[base + 0] = excl;
    if (base + 1 < NP) cursor[base + 1] = excl + v0;
    if (base + 2 < NP) cursor[base + 2] = excl + v0 + v1;
    if (base + 3 < NP) cursor[base + 3] = excl + v0 + v1 + v2;
}

// scatter edge payloads (sender H-row id); cursor[n] advances to segment end
__global__ __launch_bounds__(256) void fill_k(
    const int* __restrict__ c_src, const int* __restrict__ c_dst,
    const int* __restrict__ w_src, const int* __restrict__ w_dst,
    int* __restrict__ cursor, int* __restrict__ eidx)
{
    int i = blockIdx.x * 256 + threadIdx.x;
    if (i >= NE2) return;
    int d, val;
    if (i < NEDGE) { d = c_dst[i];         val = c_src[i]; }
    else           { int j = i - NEDGE; d = w_dst[j]; val = NP + w_src[j]; }
    int pos = atomicAdd(&cursor[d], 1);
    eidx[pos] = val;
}

// ---------------------------------------------------------------------------
// Atomic-free gather + fused self-transform + mean + bias + relu.
// 8 nodes/block, 32 lanes/node (lane l owns output cols 4l..4l+3).
// After fill_k: start(n) = (n==0 ? 0 : cursor[n-1]), end(n) = cursor[n].
// ---------------------------------------------------------------------------
__global__ __launch_bounds__(256, 2) void gather_fused(
    const float* __restrict__ H, const int* __restrict__ eidx,
    const int* __restrict__ cursor, const float* __restrict__ x_paper,
    const float* __restrict__ W_self, const float* __restrict__ bias,
    float* __restrict__ out)
{
    __shared__ float Wl[DIM * UNITS];   // 64 KB
    __shared__ float Xl[8 * DIM];       // 4 KB

    const int tid = threadIdx.x;
    const float4* Ws4 = (const float4*)W_self;
    float4*       Wl4 = (float4*)Wl;
#pragma unroll
    for (int i = 0; i < 16; ++i)
        Wl4[i * 256 + tid] = Ws4[i * 256 + tid];

    const int n0 = blockIdx.x * 8;       // NP % 8 == 0, no tail
    float4* Xl4 = (float4*)Xl;
    Xl4[tid] = ((const float4*)(x_paper + (size_t)n0 * DIM))[tid];
    __syncthreads();

    const int g = tid >> 5, l = tid & 31;
    const int n = n0 + g;

    // Self transform: acc = x[n] @ W_self[:, 4l..4l+3]
    float4 acc; acc.x = acc.y = acc.z = acc.w = 0.0f;
#pragma unroll 8
    for (int kk = 0; kk < 32; ++kk) {
        const float4 xv = Xl4[g * 32 + kk];                 // group broadcast
        const float4 w0 = Wl4[(kk * 4 + 0) * 32 + l];
        const float4 w1 = Wl4[(kk * 4 + 1) * 32 + l];
        const float4 w2 = Wl4[(kk * 4 + 2) * 32 + l];
        const float4 w3 = Wl4[(kk * 4 + 3) * 32 + l];
        acc.x = fmaf(xv.x, w0.x, acc.x); acc.y = fmaf(xv.x, w0.y, acc.y);
        acc.z = fmaf(xv.x, w0.z, acc.z); acc.w = fmaf(xv.x, w0.w, acc.w);
        acc.x = fmaf(xv.y, w1.x, acc.x); acc.y = fmaf(xv.y, w1.y, acc.y);
        acc.z = fmaf(xv.y, w1.z, acc.z); acc.w = fmaf(xv.y, w1.w, acc.w);
        acc.x = fmaf(xv.z, w2.x, acc.x); acc.y = fmaf(xv.z, w2.y, acc.y);
        acc.z = fmaf(xv.z, w2.z, acc.z); acc.w = fmaf(xv.z, w2.w, acc.w);
        acc.x = fmaf(xv.w, w3.x, acc.x); acc.y = fmaf(xv.w, w3.y, acc.y);
        acc.z = fmaf(xv.w, w3.z, acc.z); acc.w = fmaf(xv.w, w3.w, acc.w);
    }

    // In-edge gather (sequential f32 sum, no atomics). Prefetch next eidx.
    const int start = (n == 0) ? 0 : cursor[n - 1];
    const int end   = cursor[n];
    const float4* H4 = (const float4*)H;
    int e_next = (start < end) ? eidx[start] : 0;
    for (int j = start; j < end; ++j) {
        const int e = e_next;
        if (j + 1 < end) e_next = eidx[j + 1];
        const float4 v = H4[(size_t)e * 32 + l];
        acc.x += v.x; acc.y += v.y; acc.z += v.z; acc.w += v.w;
    }

    const float inv = 1.0f / (float)(end - start + 1);      // +1 self-loop
    const float4 b = ((const float4*)bias)[l];
    float4 o;
    o.x = fmaxf(fmaf(acc.x, inv, b.x), 0.0f);
    o.y = fmaxf(fmaf(acc.y, inv, b.y), 0.0f);
    o.z = fmaxf(fmaf(acc.z, inv, b.z), 0.0f);
    o.w = fmaxf(fmaf(acc.w, inv, b.w), 0.0f);
    ((float4*)out)[(size_t)n * 32 + l] = o;
}

// ---------------------------------------------------------------------------
extern "C" void kernel_launch(void* const* d_in, const int* in_sizes, int n_in,
                              void* d_out, int out_size, void* d_ws, size_t ws_size,
                              hipStream_t stream)
{
    const float* x_paper    = (const float*)d_in[0];
    const float* x_author   = (const float*)d_in[1];
    const float* W_cites    = (const float*)d_in[2];
    const float* W_writes   = (const float*)d_in[3];
    const float* W_self     = (const float*)d_in[4];
    const float* bias       = (const float*)d_in[5];
    const int*   cites_src  = (const int*)d_in[6];
    const int*   cites_dst  = (const int*)d_in[7];
    const int*   writes_src = (const int*)d_in[8];
    const int*   writes_dst = (const int*)d_in[9];
    float* out = (float*)d_out;

    // Workspace layout (~81.6 MB, well under the proven >=128.4 MB bound):
    //   H      : 150000*128 f32 = 76.8 MB  (paper rows 0..NP, author rows NP..NP+NA)
    //   eidx   : 1M int         =  4.0 MB
    //   count  : NP int         =  0.4 MB
    //   cursor : NP int         =  0.4 MB
    //   csum/coff : NCHUNK ints each
    char* ws = (char*)d_ws;
    float* H      = (float*)(ws);
    int*   eidx   = (int*)(ws + 76800000);
    int*   count  = (int*)(ws + 80800000);
    int*   cursor = (int*)(ws + 81200000);
    int*   csum   = (int*)(ws + 81600000);
    int*   coff   = (int*)(ws + 81600512);

    // Sender transforms (independent of CSR build).
    gemm_all<<<GP + GA, 256, 0, stream>>>(x_paper, x_author, W_cites, W_writes, H);

    // CSR build over both edge sets combined.
    zero_count<<<(NP + 255) / 256, 256, 0, stream>>>(count);
    hist_k<<<(NE2 + 255) / 256, 256, 0, stream>>>(cites_dst, writes_dst, count);
    scanA<<<NCHUNK, 256, 0, stream>>>(count, csum);
    scanB<<<1, 128, 0, stream>>>(csum, coff);
    scanC<<<NCHUNK, 256, 0, stream>>>(count, coff, cursor);
    fill_k<<<(NE2 + 255) / 256, 256, 0, stream>>>(
        cites_src, cites_dst, writes_src, writes_dst, cursor, eidx);

    // Atomic-free gather + self + finalize.
    gather_fused<<<NP / 8, 256, 0, stream>>>(H, eidx, cursor, x_paper, W_self, bias, out);
}

// Round 5
// 434.546 us; speedup vs baseline: 4.5812x; 1.2199x over previous
//
#include <hip/hip_runtime.h>
#include <hip/hip_bf16.h>

// Problem constants (from reference)
#define NP     100000   // papers (receivers)
#define NA     50000    // authors
#define DIM    128      // feature dim
#define UNITS  128      // output units
#define NEDGE  500000   // edges per edge set
#define NE2    (2 * NEDGE)

#define GEMM_ROWS 32
#define GP (NP / GEMM_ROWS)                       // 3125 (exact)
#define GA ((NA + GEMM_ROWS - 1) / GEMM_ROWS)     // 1563

#define CHUNK  1024
#define NCHUNK ((NP + CHUNK - 1) / CHUNK)         // 98

// ---------------------------------------------------------------------------
// Sender + self transforms (atomic-free), one dispatch:
//   blocks [0, GP)            : H[0..NP)     = x_paper  @ W_cites
//   blocks [GP, GP+GA)        : H[NP..+NA)   = x_author @ W_writes
//   blocks [GP+GA, 2GP+GA)    : out[0..NP)   = x_paper  @ W_self   (pre-gather)
// W in LDS (64 KB) + 32-row X tile (16 KB) -> 2 blocks/CU. 4x4 reg tiles.
// ---------------------------------------------------------------------------
__global__ __launch_bounds__(256, 2) void gemm_all(
    const float* __restrict__ x_paper, const float* __restrict__ x_author,
    const float* __restrict__ W_cites, const float* __restrict__ W_writes,
    const float* __restrict__ W_self,
    float* __restrict__ H, float* __restrict__ out)
{
    const float* X; const float* W; float* Ho; int nrows; int bb;
    if (blockIdx.x < GP) {
        X = x_paper;  W = W_cites;  Ho = H;                      nrows = NP; bb = blockIdx.x;
    } else if (blockIdx.x < GP + GA) {
        X = x_author; W = W_writes; Ho = H + (size_t)NP * UNITS; nrows = NA; bb = blockIdx.x - GP;
    } else {
        X = x_paper;  W = W_self;   Ho = out;                    nrows = NP; bb = blockIdx.x - GP - GA;
    }

    __shared__ float Wl[DIM * UNITS];       // 64 KB
    __shared__ float Xl[GEMM_ROWS * DIM];   // 16 KB

    const int tid  = threadIdx.x;
    const int row0 = bb * GEMM_ROWS;

    const float4* W4  = (const float4*)W;
    float4*       Wl4 = (float4*)Wl;
#pragma unroll
    for (int i = 0; i < 16; ++i)
        Wl4[i * 256 + tid] = W4[i * 256 + tid];

    const float4* X4  = (const float4*)(X + (size_t)row0 * DIM);
    float4*       Xl4 = (float4*)Xl;
#pragma unroll
    for (int i = 0; i < 4; ++i) {
        int idx = i * 256 + tid;
        if (row0 + (idx >> 5) < nrows)
            Xl4[idx] = X4[idx];
    }
    __syncthreads();

    const int ug = tid & 31;
    const int rg = tid >> 5;
    const int r0 = rg * 4;

    float acc[4][4];
#pragma unroll
    for (int r = 0; r < 4; ++r)
#pragma unroll
        for (int j = 0; j < 4; ++j) acc[r][j] = 0.0f;

#pragma unroll 4
    for (int kk = 0; kk < 32; ++kk) {
        float4 xv[4], wv[4];
#pragma unroll
        for (int r = 0; r < 4; ++r) xv[r] = Xl4[(r0 + r) * 32 + kk];       // broadcast
#pragma unroll
        for (int i = 0; i < 4; ++i) wv[i] = Wl4[(kk * 4 + i) * 32 + ug];   // linear
#pragma unroll
        for (int r = 0; r < 4; ++r) {
            const float xr0 = xv[r].x, xr1 = xv[r].y, xr2 = xv[r].z, xr3 = xv[r].w;
            acc[r][0] = fmaf(xr0, wv[0].x, acc[r][0]);
            acc[r][1] = fmaf(xr0, wv[0].y, acc[r][1]);
            acc[r][2] = fmaf(xr0, wv[0].z, acc[r][2]);
            acc[r][3] = fmaf(xr0, wv[0].w, acc[r][3]);
            acc[r][0] = fmaf(xr1, wv[1].x, acc[r][0]);
            acc[r][1] = fmaf(xr1, wv[1].y, acc[r][1]);
            acc[r][2] = fmaf(xr1, wv[1].z, acc[r][2]);
            acc[r][3] = fmaf(xr1, wv[1].w, acc[r][3]);
            acc[r][0] = fmaf(xr2, wv[2].x, acc[r][0]);
            acc[r][1] = fmaf(xr2, wv[2].y, acc[r][1]);
            acc[r][2] = fmaf(xr2, wv[2].z, acc[r][2]);
            acc[r][3] = fmaf(xr2, wv[2].w, acc[r][3]);
            acc[r][0] = fmaf(xr3, wv[3].x, acc[r][0]);
            acc[r][1] = fmaf(xr3, wv[3].y, acc[r][1]);
            acc[r][2] = fmaf(xr3, wv[3].z, acc[r][2]);
            acc[r][3] = fmaf(xr3, wv[3].w, acc[r][3]);
        }
    }

    float4* H4 = (float4*)Ho;
#pragma unroll
    for (int r = 0; r < 4; ++r) {
        int row = row0 + r0 + r;
        if (row < nrows) {
            float4 v; v.x = acc[r][0]; v.y = acc[r][1]; v.z = acc[r][2]; v.w = acc[r][3];
            H4[(size_t)row * 32 + ug] = v;
        }
    }
}

// ---------------------------------------------------------------------------
// CSR build: zero -> hist -> scan(A,B,C) -> fill
// ---------------------------------------------------------------------------
__global__ __launch_bounds__(256) void zero_count(int* __restrict__ count)
{
    int i = blockIdx.x * 256 + threadIdx.x;
    if (i < NP) count[i] = 0;
}

__global__ __launch_bounds__(256) void hist_k(
    const int* __restrict__ c_dst, const int* __restrict__ w_dst,
    int* __restrict__ count)
{
    int i = blockIdx.x * 256 + threadIdx.x;
    if (i >= NE2) return;
    int d = (i < NEDGE) ? c_dst[i] : w_dst[i - NEDGE];
    atomicAdd(&count[d], 1);
}

// per-1024-chunk sums
__global__ __launch_bounds__(256) void scanA(
    const int* __restrict__ count, int* __restrict__ csum)
{
    __shared__ int red[256];
    const int c = blockIdx.x, t = threadIdx.x;
    const int base = c * CHUNK + t * 4;
    int s = 0;
#pragma unroll
    for (int r = 0; r < 4; ++r)
        if (base + r < NP) s += count[base + r];
    red[t] = s; __syncthreads();
#pragma unroll
    for (int off = 128; off > 0; off >>= 1) {
        if (t < off) red[t] += red[t + off];
        __syncthreads();
    }
    if (t == 0) csum[c] = red[0];
}

// exclusive scan of the NCHUNK chunk sums (NCHUNK <= 128)
__global__ __launch_bounds__(128) void scanB(
    const int* __restrict__ csum, int* __restrict__ coff)
{
    __shared__ int ts[128];
    const int t = threadIdx.x;
    const int v = (t < NCHUNK) ? csum[t] : 0;
    ts[t] = v; __syncthreads();
    for (int off = 1; off < 128; off <<= 1) {
        int x = (t >= off) ? ts[t - off] : 0;
        __syncthreads();
        ts[t] += x;
        __syncthreads();
    }
    if (t < NCHUNK) coff[t] = ts[t] - v;   // exclusive
}

// in-chunk exclusive scan -> cursor[] = segment starts
__global__ __launch_bounds__(256) void scanC(
    const int* __restrict__ count, const int* __restrict__ coff,
    int* __restrict__ cursor)
{
    __shared__ int ts[256];
    const int c = blockIdx.x, t = threadIdx.x;
    const int base = c * CHUNK + t * 4;
    int v0 = 0, v1 = 0, v2 = 0, v3 = 0;
    if (base + 0 < NP) v0 = count[base + 0];
    if (base + 1 < NP) v1 = count[base + 1];
    if (base + 2 < NP) v2 = count[base + 2];
    if (base + 3 < NP) v3 = count[base + 3];
    const int s = v0 + v1 + v2 + v3;
    ts[t] = s; __syncthreads();
    for (int off = 1; off < 256; off <<= 1) {
        int x = (t >= off) ? ts[t - off] : 0;
        __syncthreads();
        ts[t] += x;
        __syncthreads();
    }
    int excl = ts[t] - s + coff[c];
    if (base + 0 < NP) cursor[base + 0] = excl;
    if (base + 1 < NP) cursor[base + 1] = excl + v0;
    if (base + 2 < NP) cursor[base + 2] = excl + v0 + v1;
    if (base + 3 < NP) cursor[base + 3] = excl + v0 + v1 + v2;
}

// scatter edge payloads (sender H-row id); cursor[n] advances to segment end
__global__ __launch_bounds__(256) void fill_k(
    const int* __restrict__ c_src, const int* __restrict__ c_dst,
    const int* __restrict__ w_src, const int* __restrict__ w_dst,
    int* __restrict__ cursor, int* __restrict__ eidx)
{
    int i = blockIdx.x * 256 + threadIdx.x;
    if (i >= NE2) return;
    int d, val;
    if (i < NEDGE) { d = c_dst[i];         val = c_src[i]; }
    else           { int j = i - NEDGE; d = w_dst[j]; val = NP + w_src[j]; }
    int pos = atomicAdd(&cursor[d], 1);
    eidx[pos] = val;
}

// ---------------------------------------------------------------------------
// Atomic-free gather + mean + bias + relu. Self term pre-written into out[].
// 8 nodes/block, 32 lanes/node (lane l owns output cols 4l..4l+3).
// No LDS, low VGPR -> high occupancy; loads are L2/L3-resident random rows.
// After fill_k: start(n) = (n==0 ? 0 : cursor[n-1]), end(n) = cursor[n].
// ---------------------------------------------------------------------------
__global__ __launch_bounds__(256) void gather_fused(
    const float* __restrict__ H, const int* __restrict__ eidx,
    const int* __restrict__ cursor, const float* __restrict__ bias,
    float* __restrict__ out)
{
    const int tid = threadIdx.x;
    const int g = tid >> 5, l = tid & 31;
    const int n = blockIdx.x * 8 + g;      // NP % 8 == 0, no tail

    // Start from the self-transform value written by gemm_all.
    float4 acc = ((const float4*)out)[(size_t)n * 32 + l];

    const int start = (n == 0) ? 0 : cursor[n - 1];
    const int end   = cursor[n];
    const float4* H4 = (const float4*)H;
    int e_next = (start < end) ? eidx[start] : 0;
    for (int j = start; j < end; ++j) {
        const int e = e_next;
        if (j + 1 < end) e_next = eidx[j + 1];
        const float4 v = H4[(size_t)e * 32 + l];
        acc.x += v.x; acc.y += v.y; acc.z += v.z; acc.w += v.w;
    }

    const float inv = 1.0f / (float)(end - start + 1);      // +1 self-loop
    const float4 b = ((const float4*)bias)[l];
    float4 o;
    o.x = fmaxf(fmaf(acc.x, inv, b.x), 0.0f);
    o.y = fmaxf(fmaf(acc.y, inv, b.y), 0.0f);
    o.z = fmaxf(fmaf(acc.z, inv, b.z), 0.0f);
    o.w = fmaxf(fmaf(acc.w, inv, b.w), 0.0f);
    ((float4*)out)[(size_t)n * 32 + l] = o;
}

// ---------------------------------------------------------------------------
extern "C" void kernel_launch(void* const* d_in, const int* in_sizes, int n_in,
                              void* d_out, int out_size, void* d_ws, size_t ws_size,
                              hipStream_t stream)
{
    const float* x_paper    = (const float*)d_in[0];
    const float* x_author   = (const float*)d_in[1];
    const float* W_cites    = (const float*)d_in[2];
    const float* W_writes   = (const float*)d_in[3];
    const float* W_self     = (const float*)d_in[4];
    const float* bias       = (const float*)d_in[5];
    const int*   cites_src  = (const int*)d_in[6];
    const int*   cites_dst  = (const int*)d_in[7];
    const int*   writes_src = (const int*)d_in[8];
    const int*   writes_dst = (const int*)d_in[9];
    float* out = (float*)d_out;

    // Workspace (~81.6 MB):
    //   H      : 150000*128 f32 = 76.8 MB (papers 0..NP, authors NP..NP+NA)
    //   eidx   : 1M int  = 4.0 MB
    //   count/cursor : NP int each
    //   csum/coff    : NCHUNK int each
    char* ws = (char*)d_ws;
    float* H      = (float*)(ws);
    int*   eidx   = (int*)(ws + 76800000);
    int*   count  = (int*)(ws + 80800000);
    int*   cursor = (int*)(ws + 81200000);
    int*   csum   = (int*)(ws + 81600000);
    int*   coff   = (int*)(ws + 81600512);

    // All three transforms (self -> out, read back by gather_fused).
    gemm_all<<<2 * GP + GA, 256, 0, stream>>>(
        x_paper, x_author, W_cites, W_writes, W_self, H, out);

    // CSR build over both edge sets combined.
    zero_count<<<(NP + 255) / 256, 256, 0, stream>>>(count);
    hist_k<<<(NE2 + 255) / 256, 256, 0, stream>>>(cites_dst, writes_dst, count);
    scanA<<<NCHUNK, 256, 0, stream>>>(count, csum);
    scanB<<<1, 128, 0, stream>>>(csum, coff);
    scanC<<<NCHUNK, 256, 0, stream>>>(count, coff, cursor);
    fill_k<<<(NE2 + 255) / 256, 256, 0, stream>>>(
        cites_src, cites_dst, writes_src, writes_dst, cursor, eidx);

    // Atomic-free gather + finalize (reads self term from out, overwrites out).
    gather_fused<<<NP / 8, 256, 0, stream>>>(H, eidx, cursor, bias, out);
}

// Round 7
// 393.918 us; speedup vs baseline: 5.0537x; 1.1031x over previous
//
#include <hip/hip_runtime.h>
#include <hip/hip_bf16.h>

// Problem constants (from reference)
#define NP     100000   // papers (receivers)
#define NA     50000    // authors
#define DIM    128      // feature dim
#define UNITS  128      // output units
#define NEDGE  500000   // edges per edge set
#define NE2    (2 * NEDGE)

#define BM   128                              // rows per GEMM block
#define GPB  ((NP + BM - 1) / BM)             // 782
#define GAB  ((NA + BM - 1) / BM)             // 391

#define CHUNK  1024
#define NCHUNK ((NP + CHUNK - 1) / CHUNK)     // 98

typedef __attribute__((ext_vector_type(8))) short bfrag;   // 8 bf16 = 4 VGPR
typedef __attribute__((ext_vector_type(4))) float f32x4;   // MFMA accum

__device__ __forceinline__ unsigned int bf_rne(float x) {  // f32 -> bf16 bits (RNE)
    unsigned int u = __builtin_bit_cast(unsigned int, x);
    u += 0x7FFFu + ((u >> 16) & 1u);
    return u >> 16;
}
__device__ __forceinline__ float bf_to_f(unsigned int b) {
    unsigned int u = b << 16;
    return __builtin_bit_cast(float, u);
}

// ---------------------------------------------------------------------------
// bf16-split MFMA GEMM: Ho[0..nrows) = X[0..nrows) @ W  (f32 in/out)
//   blocks [0, GPB)            : H[0..NP)    = x_paper  @ W_cites
//   blocks [GPB, GPB+GAB)      : H[NP..+NA)  = x_author @ W_writes
//   blocks [GPB+GAB, ..)       : out[0..NP)  = x_paper  @ W_self
// Split: x = hi + lo (bf16); acc += Ahi*Bhi + Ahi*Blo + Alo*Bhi (f32 accum);
// dropped lo*lo term is ~2^-16 relative.
// LDS k-octet layout: elem (r, k) lives at short idx (k>>3)*1024 + r*8 + (k&7)
// (r = X row or W col), so an mfma_f32_16x16x32_bf16 fragment (lane l:
// r = base + (l&15), k-octet = l>>4) is ONE 16-B ds_read. X side additionally
// XOR-swizzled: slot (k>>3)*128 + (r ^ (k>>3)) in uint4 units, so that
// koct-fastest staging writes don't collide (writes & reads both <=2-way).
// 4 waves in 2x2, each 64x64 out (16 tiles, K=128, 192 MFMA).
// 128 KB LDS -> 1 block/CU.
// ---------------------------------------------------------------------------
__global__ __launch_bounds__(256, 1) void mfma_gemm_all(
    const float* __restrict__ x_paper, const float* __restrict__ x_author,
    const float* __restrict__ W_cites, const float* __restrict__ W_writes,
    const float* __restrict__ W_self,
    float* __restrict__ H, float* __restrict__ out)
{
    const float* X; const float* W; float* Ho; int nrows; int bb;
    if (blockIdx.x < GPB) {
        X = x_paper;  W = W_cites;  Ho = H;                      nrows = NP; bb = blockIdx.x;
    } else if (blockIdx.x < GPB + GAB) {
        X = x_author; W = W_writes; Ho = H + (size_t)NP * UNITS; nrows = NA; bb = blockIdx.x - GPB;
    } else {
        X = x_paper;  W = W_self;   Ho = out;                    nrows = NP; bb = blockIdx.x - GPB - GAB;
    }

    __shared__ unsigned short Xhi[BM * DIM];    // 32 KB each, 128 KB total
    __shared__ unsigned short Xlo[BM * DIM];
    __shared__ unsigned short Whi[DIM * UNITS];
    __shared__ unsigned short Wlo[DIM * UNITS];

    const int tid  = threadIdx.x;
    const int row0 = bb * BM;

    // ---- Stage W (transpose k-major -> col-octet layout).
    // item: n = item&127 (lane-fastest -> coalesced loads, consecutive b128
    // writes), koct = item>>7. 8 strided dword loads per item (L2-resident W).
#pragma unroll
    for (int i = 0; i < 8; ++i) {
        const int item = i * 256 + tid;          // 0..2047
        const int n    = item & 127;
        const int koct = item >> 7;              // 0..15
        unsigned int h[8], l[8];
#pragma unroll
        for (int j = 0; j < 8; ++j) {
            const float e = W[(size_t)(koct * 8 + j) * UNITS + n];
            h[j] = bf_rne(e);
            l[j] = bf_rne(e - bf_to_f(h[j]));
        }
        uint4 hv, lv;
        hv.x = h[0] | (h[1] << 16); hv.y = h[2] | (h[3] << 16);
        hv.z = h[4] | (h[5] << 16); hv.w = h[6] | (h[7] << 16);
        lv.x = l[0] | (l[1] << 16); lv.y = l[2] | (l[3] << 16);
        lv.z = l[4] | (l[5] << 16); lv.w = l[6] | (l[7] << 16);
        const int slot = koct * 128 + n;         // uint4 units, no swizzle
        ((uint4*)Whi)[slot] = hv;
        ((uint4*)Wlo)[slot] = lv;
    }

    // ---- Stage X tile (row-major -> row-octet layout, XOR-swizzled).
    // item: koct = item&15 (lane-fastest -> coalesced 32B loads), row = item>>4.
    const float4* X4 = (const float4*)(X + (size_t)row0 * DIM);
#pragma unroll
    for (int i = 0; i < 8; ++i) {
        const int item = i * 256 + tid;          // 0..2047
        const int koct = item & 15;
        const int row  = item >> 4;              // 0..127
        if (row0 + row < nrows) {
            const float4 v0 = X4[row * 32 + koct * 2];
            const float4 v1 = X4[row * 32 + koct * 2 + 1];
            const float e[8] = {v0.x, v0.y, v0.z, v0.w, v1.x, v1.y, v1.z, v1.w};
            unsigned int h[8], l[8];
#pragma unroll
            for (int j = 0; j < 8; ++j) {
                h[j] = bf_rne(e[j]);
                l[j] = bf_rne(e[j] - bf_to_f(h[j]));
            }
            uint4 hv, lv;
            hv.x = h[0] | (h[1] << 16); hv.y = h[2] | (h[3] << 16);
            hv.z = h[4] | (h[5] << 16); hv.w = h[6] | (h[7] << 16);
            lv.x = l[0] | (l[1] << 16); lv.y = l[2] | (l[3] << 16);
            lv.z = l[4] | (l[5] << 16); lv.w = l[6] | (l[7] << 16);
            const int slot = koct * 128 + (row ^ koct);   // swizzled uint4 slot
            ((uint4*)Xhi)[slot] = hv;
            ((uint4*)Xlo)[slot] = lv;
        }
    }
    __syncthreads();

    // ---- Compute: wave (wr,wc) owns 64x64; 4x4 tiles of 16x16, K=128.
    const int lane = tid & 63;
    const int wv   = tid >> 6;
    const int wr   = (wv >> 1) * 64;
    const int wc   = (wv & 1) * 64;
    const int l16  = lane & 15;
    const int q    = lane >> 4;

    f32x4 acc[4][4];
#pragma unroll
    for (int rt = 0; rt < 4; ++rt)
#pragma unroll
        for (int ct = 0; ct < 4; ++ct) acc[rt][ct] = (f32x4)(0.0f);

#pragma unroll
    for (int kk = 0; kk < 4; ++kk) {
        const int fb = kk * 4 + q;               // k-octet 0..15
        bfrag ah[4], al[4], bh[4], bl[4];
#pragma unroll
        for (int rt = 0; rt < 4; ++rt) {
            const int row = wr + rt * 16 + l16;
            const int off = (fb * 128 + (row ^ fb)) * 8;     // shorts
            ah[rt] = *(const bfrag*)&Xhi[off];
            al[rt] = *(const bfrag*)&Xlo[off];
        }
#pragma unroll
        for (int ct = 0; ct < 4; ++ct) {
            const int off = (fb * 128 + wc + ct * 16 + l16) * 8;
            bh[ct] = *(const bfrag*)&Whi[off];
            bl[ct] = *(const bfrag*)&Wlo[off];
        }
#pragma unroll
        for (int rt = 0; rt < 4; ++rt)
#pragma unroll
            for (int ct = 0; ct < 4; ++ct) {
                acc[rt][ct] = __builtin_amdgcn_mfma_f32_16x16x32_bf16(
                    ah[rt], bh[ct], acc[rt][ct], 0, 0, 0);
                acc[rt][ct] = __builtin_amdgcn_mfma_f32_16x16x32_bf16(
                    ah[rt], bl[ct], acc[rt][ct], 0, 0, 0);
                acc[rt][ct] = __builtin_amdgcn_mfma_f32_16x16x32_bf16(
                    al[rt], bh[ct], acc[rt][ct], 0, 0, 0);
            }
    }

    // ---- Store. D elem r of a tile: row = (lane>>4)*4 + r, col = lane&15.
#pragma unroll
    for (int rt = 0; rt < 4; ++rt) {
#pragma unroll
        for (int r = 0; r < 4; ++r) {
            const int row = wr + rt * 16 + q * 4 + r;
            if (row0 + row < nrows) {
                float* dst = Ho + (size_t)(row0 + row) * UNITS + wc + l16;
#pragma unroll
                for (int ct = 0; ct < 4; ++ct) dst[ct * 16] = acc[rt][ct][r];
            }
        }
    }
}

// ---------------------------------------------------------------------------
// CSR build: zero -> hist -> scan(A,B,C) -> fill
// ---------------------------------------------------------------------------
__global__ __launch_bounds__(256) void zero_count(int* __restrict__ count)
{
    int i = blockIdx.x * 256 + threadIdx.x;
    if (i < NP) count[i] = 0;
}

__global__ __launch_bounds__(256) void hist_k(
    const int* __restrict__ c_dst, const int* __restrict__ w_dst,
    int* __restrict__ count)
{
    int i = blockIdx.x * 256 + threadIdx.x;
    if (i >= NE2) return;
    int d = (i < NEDGE) ? c_dst[i] : w_dst[i - NEDGE];
    atomicAdd(&count[d], 1);
}

// per-1024-chunk sums
__global__ __launch_bounds__(256) void scanA(
    const int* __restrict__ count, int* __restrict__ csum)
{
    __shared__ int red[256];
    const int c = blockIdx.x, t = threadIdx.x;
    const int base = c * CHUNK + t * 4;
    int s = 0;
#pragma unroll
    for (int r = 0; r < 4; ++r)
        if (base + r < NP) s += count[base + r];
    red[t] = s; __syncthreads();
#pragma unroll
    for (int off = 128; off > 0; off >>= 1) {
        if (t < off) red[t] += red[t + off];
        __syncthreads();
    }
    if (t == 0) csum[c] = red[0];
}

// exclusive scan of the NCHUNK chunk sums (NCHUNK <= 128)
__global__ __launch_bounds__(128) void scanB(
    const int* __restrict__ csum, int* __restrict__ coff)
{
    __shared__ int ts[128];
    const int t = threadIdx.x;
    const int v = (t < NCHUNK) ? csum[t] : 0;
    ts[t] = v; __syncthreads();
    for (int off = 1; off < 128; off <<= 1) {
        int x = (t >= off) ? ts[t - off] : 0;
        __syncthreads();
        ts[t] += x;
        __syncthreads();
    }
    if (t < NCHUNK) coff[t] = ts[t] - v;   // exclusive
}

// in-chunk exclusive scan -> cursor[] = segment starts
__global__ __launch_bounds__(256) void scanC(
    const int* __restrict__ count, const int* __restrict__ coff,
    int* __restrict__ cursor)
{
    __shared__ int ts[256];
    const int c = blockIdx.x, t = threadIdx.x;
    const int base = c * CHUNK + t * 4;
    int v0 = 0, v1 = 0, v2 = 0, v3 = 0;
    if (base + 0 < NP) v0 = count[base + 0];
    if (base + 1 < NP) v1 = count[base + 1];
    if (base + 2 < NP) v2 = count[base + 2];
    if (base + 3 < NP) v3 = count[base + 3];
    const int s = v0 + v1 + v2 + v3;
    ts[t] = s; __syncthreads();
    for (int off = 1; off < 256; off <<= 1) {
        int x = (t >= off) ? ts[t - off] : 0;
        __syncthreads();
        ts[t] += x;
        __syncthreads();
    }
    int excl = ts[t] - s + coff[c];
    if (base + 0 < NP) cursor[base + 0] = excl;
    if (base + 1 < NP) cursor[base + 1] = excl + v0;
    if (base + 2 < NP) cursor[base + 2] = excl + v0 + v1;
    if (base + 3 < NP) cursor[base + 3] = excl + v0 + v1 + v2;
}

// scatter edge payloads (sender H-row id); cursor[n] advances to segment end
__global__ __launch_bounds__(256) void fill_k(
    const int* __restrict__ c_src, const int* __restrict__ c_dst,
    const int* __restrict__ w_src, const int* __restrict__ w_dst,
    int* __restrict__ cursor, int* __restrict__ eidx)
{
    int i = blockIdx.x * 256 + threadIdx.x;
    if (i >= NE2) return;
    int d, val;
    if (i < NEDGE) { d = c_dst[i];         val = c_src[i]; }
    else           { int j = i - NEDGE; d = w_dst[j]; val = NP + w_src[j]; }
    int pos = atomicAdd(&cursor[d], 1);
    eidx[pos] = val;
}

// ---------------------------------------------------------------------------
// Atomic-free gather + mean + bias + relu. Self term pre-written into out[].
// 8 nodes/block, 32 lanes/node (lane l owns output cols 4l..4l+3).
// ---------------------------------------------------------------------------
__global__ __launch_bounds__(256) void gather_fused(
    const float* __restrict__ H, const int* __restrict__ eidx,
    const int* __restrict__ cursor, const float* __restrict__ bias,
    float* __restrict__ out)
{
    const int tid = threadIdx.x;
    const int g = tid >> 5, l = tid & 31;
    const int n = blockIdx.x * 8 + g;      // NP % 8 == 0, no tail

    float4 acc = ((const float4*)out)[(size_t)n * 32 + l];

    const int start = (n == 0) ? 0 : cursor[n - 1];
    const int end   = cursor[n];
    const float4* H4 = (const float4*)H;
    int e_next = (start < end) ? eidx[start] : 0;
    for (int j = start; j < end; ++j) {
        const int e = e_next;
        if (j + 1 < end) e_next = eidx[j + 1];
        const float4 v = H4[(size_t)e * 32 + l];
        acc.x += v.x; acc.y += v.y; acc.z += v.z; acc.w += v.w;
    }

    const float inv = 1.0f / (float)(end - start + 1);      // +1 self-loop
    const float4 b = ((const float4*)bias)[l];
    float4 o;
    o.x = fmaxf(fmaf(acc.x, inv, b.x), 0.0f);
    o.y = fmaxf(fmaf(acc.y, inv, b.y), 0.0f);
    o.z = fmaxf(fmaf(acc.z, inv, b.z), 0.0f);
    o.w = fmaxf(fmaf(acc.w, inv, b.w), 0.0f);
    ((float4*)out)[(size_t)n * 32 + l] = o;
}

// ---------------------------------------------------------------------------
extern "C" void kernel_launch(void* const* d_in, const int* in_sizes, int n_in,
                              void* d_out, int out_size, void* d_ws, size_t ws_size,
                              hipStream_t stream)
{
    const float* x_paper    = (const float*)d_in[0];
    const float* x_author   = (const float*)d_in[1];
    const float* W_cites    = (const float*)d_in[2];
    const float* W_writes   = (const float*)d_in[3];
    const float* W_self     = (const float*)d_in[4];
    const float* bias       = (const float*)d_in[5];
    const int*   cites_src  = (const int*)d_in[6];
    const int*   cites_dst  = (const int*)d_in[7];
    const int*   writes_src = (const int*)d_in[8];
    const int*   writes_dst = (const int*)d_in[9];
    float* out = (float*)d_out;

    // Workspace (~81.6 MB):
    //   H      : 150000*128 f32 = 76.8 MB (papers 0..NP, authors NP..NP+NA)
    //   eidx   : 1M int  = 4.0 MB
    //   count/cursor : NP int each; csum/coff : NCHUNK int each
    char* ws = (char*)d_ws;
    float* H      = (float*)(ws);
    int*   eidx   = (int*)(ws + 76800000);
    int*   count  = (int*)(ws + 80800000);
    int*   cursor = (int*)(ws + 81200000);
    int*   csum   = (int*)(ws + 81600000);
    int*   coff   = (int*)(ws + 81600512);

    // All three transforms via bf16-split MFMA (self -> out).
    mfma_gemm_all<<<2 * GPB + GAB, 256, 0, stream>>>(
        x_paper, x_author, W_cites, W_writes, W_self, H, out);

    // CSR build over both edge sets combined.
    zero_count<<<(NP + 255) / 256, 256, 0, stream>>>(count);
    hist_k<<<(NE2 + 255) / 256, 256, 0, stream>>>(cites_dst, writes_dst, count);
    scanA<<<NCHUNK, 256, 0, stream>>>(count, csum);
    scanB<<<1, 128, 0, stream>>>(csum, coff);
    scanC<<<NCHUNK, 256, 0, stream>>>(count, coff, cursor);
    fill_k<<<(NE2 + 255) / 256, 256, 0, stream>>>(
        cites_src, cites_dst, writes_src, writes_dst, cursor, eidx);

    // Atomic-free gather + finalize (reads self term from out, overwrites out).
    gather_fused<<<NP / 8, 256, 0, stream>>>(H, eidx, cursor, bias, out);
}

// Round 12
// 387.469 us; speedup vs baseline: 5.1379x; 1.0166x over previous
//
#include <hip/hip_runtime.h>
#include <hip/hip_bf16.h>

// Problem constants (from reference)
#define NP     100000   // papers (receivers)
#define NA     50000    // authors
#define DIM    128      // feature dim
#define UNITS  128      // output units
#define NEDGE  500000   // edges per edge set
#define NE2    (2 * NEDGE)

#define BM   128                              // rows per GEMM block
#define GPB  ((NP + BM - 1) / BM)             // 782
#define GAB  ((NA + BM - 1) / BM)             // 391

#define CHUNK  1024
#define NCHUNK ((NP + CHUNK - 1) / CHUNK)     // 98

typedef __attribute__((ext_vector_type(8))) short bfrag;   // 8 bf16 = 4 VGPR
typedef __attribute__((ext_vector_type(4))) float f32x4;   // MFMA accum

typedef const __attribute__((address_space(1))) unsigned int* gptr_u32;
typedef __attribute__((address_space(3))) unsigned int*       lptr_u32;

__device__ __forceinline__ unsigned int bf_rne(float x) {  // f32 -> bf16 bits (RNE)
    unsigned int u = __builtin_bit_cast(unsigned int, x);
    u += 0x7FFFu + ((u >> 16) & 1u);
    return u >> 16;
}
__device__ __forceinline__ float bf_to_f(unsigned int b) {
    unsigned int u = b << 16;
    return __builtin_bit_cast(float, u);
}
__device__ __forceinline__ void gload_lds16(const void* g, void* l) {
    __builtin_amdgcn_global_load_lds((gptr_u32)g, (lptr_u32)l, 16, 0, 0);
}

// ---------------------------------------------------------------------------
// W pre-pack (blocks 0..2) + count zero-init (blocks 3..).
// Packs W[id] (f32 k-major 128x128) into split-bf16 col-octet fragment layout:
//   blob id (64 KB): uint4 slot [koct*128 + n] = hi octet (k = 8*koct..+7, col n)
//                    uint4 slot [2048 + same]  = lo octet
// Coalesced reads (n lane-fastest) and writes. 3 blocks of real work/launch.
// ---------------------------------------------------------------------------
__global__ __launch_bounds__(256) void wpack_zero(
    const float* __restrict__ W_cites, const float* __restrict__ W_writes,
    const float* __restrict__ W_self,
    unsigned short* __restrict__ Wpk, int* __restrict__ count)
{
    const int b = blockIdx.x;
    if (b < 3) {
        const float* W = (b == 0) ? W_cites : (b == 1) ? W_writes : W_self;
        uint4* dst = (uint4*)(Wpk + (size_t)b * 32768);   // 64 KB blob
        const int tid = threadIdx.x;
#pragma unroll
        for (int i = 0; i < 8; ++i) {
            const int item = i * 256 + tid;      // 0..2047
            const int n    = item & 127;
            const int koct = item >> 7;          // 0..15
            unsigned int h[8], l[8];
#pragma unroll
            for (int j = 0; j < 8; ++j) {
                const float e = W[(size_t)(koct * 8 + j) * UNITS + n];
                h[j] = bf_rne(e);
                l[j] = bf_rne(e - bf_to_f(h[j]));
            }
            uint4 hv, lv;
            hv.x = h[0] | (h[1] << 16); hv.y = h[2] | (h[3] << 16);
            hv.z = h[4] | (h[5] << 16); hv.w = h[6] | (h[7] << 16);
            lv.x = l[0] | (l[1] << 16); lv.y = l[2] | (l[3] << 16);
            lv.z = l[4] | (l[5] << 16); lv.w = l[6] | (l[7] << 16);
            dst[koct * 128 + n]        = hv;
            dst[2048 + koct * 128 + n] = lv;
        }
    } else {
        const int i = (b - 3) * 256 + threadIdx.x;
        if (i < NP) count[i] = 0;
    }
}

// ---------------------------------------------------------------------------
// bf16-split MFMA GEMM: Ho = X @ W (f32 in/out), W staged by DMA from Wpk.
//   blocks [0, GPB)            : H[0..NP)    = x_paper  @ W_cites
//   blocks [GPB, GPB+GAB)      : H[NP..+NA)  = x_author @ W_writes
//   blocks [GPB+GAB, ..)       : out[0..NP)  = x_paper  @ W_self
// acc += Ahi*Bhi + Ahi*Blo + Alo*Bhi (dropped lo*lo ~ 2^-16 relative).
// X LDS k-octet layout, XOR-swizzled (uint4 slot koct*128 + (row^koct));
// W LDS = DMA'd packed blob (hi shorts [0,16K), lo [16K,32K)), conflict-free.
// 4 waves 2x2, each 64x64 (16 tiles, K=128, 192 MFMA). 128 KB LDS, 1 blk/CU.
// ---------------------------------------------------------------------------
__global__ __launch_bounds__(256, 1) void mfma_gemm_all(
    const float* __restrict__ x_paper, const float* __restrict__ x_author,
    const unsigned short* __restrict__ Wpk,
    float* __restrict__ H, float* __restrict__ out)
{
    const float* X; float* Ho; int nrows; int bb; int wid;
    if (blockIdx.x < GPB) {
        X = x_paper;  Ho = H;                      nrows = NP; bb = blockIdx.x;             wid = 0;
    } else if (blockIdx.x < GPB + GAB) {
        X = x_author; Ho = H + (size_t)NP * UNITS; nrows = NA; bb = blockIdx.x - GPB;       wid = 1;
    } else {
        X = x_paper;  Ho = out;                    nrows = NP; bb = blockIdx.x - GPB - GAB; wid = 2;
    }

    __shared__ unsigned short Xhi[BM * DIM];        // 32 KB
    __shared__ unsigned short Xlo[BM * DIM];        // 32 KB
    __shared__ unsigned short Wl[2 * DIM * UNITS];  // 64 KB: [hi 16K][lo 16K] shorts

    const int tid  = threadIdx.x;
    const int lane = tid & 63;
    const int wv   = tid >> 6;
    const int row0 = bb * BM;

    // ---- W stage: pure DMA, issued first so it overlaps the X staging VALU.
    // Each wave covers 16 KB: 16 iters x (64 lanes x 16 B), LDS base
    // wave-uniform, global source per-lane (linear copy).
    {
        const char* gW = (const char*)Wpk + (size_t)wid * 65536;
        char*       lW = (char*)Wl;
#pragma unroll
        for (int i = 0; i < 16; ++i) {
            const int off = wv * 16384 + i * 1024;
            gload_lds16(gW + off + lane * 16, lW + off);
        }
    }

    // ---- X stage (VALU split-convert, XOR-swizzled uint4 writes).
    const float4* X4 = (const float4*)(X + (size_t)row0 * DIM);
#pragma unroll
    for (int i = 0; i < 8; ++i) {
        const int item = i * 256 + tid;          // 0..2047
        const int koct = item & 15;
        const int row  = item >> 4;              // 0..127
        if (row0 + row < nrows) {
            const float4 v0 = X4[row * 32 + koct * 2];
            const float4 v1 = X4[row * 32 + koct * 2 + 1];
            const float e[8] = {v0.x, v0.y, v0.z, v0.w, v1.x, v1.y, v1.z, v1.w};
            unsigned int h[8], l[8];
#pragma unroll
            for (int j = 0; j < 8; ++j) {
                h[j] = bf_rne(e[j]);
                l[j] = bf_rne(e[j] - bf_to_f(h[j]));
            }
            uint4 hv, lv;
            hv.x = h[0] | (h[1] << 16); hv.y = h[2] | (h[3] << 16);
            hv.z = h[4] | (h[5] << 16); hv.w = h[6] | (h[7] << 16);
            lv.x = l[0] | (l[1] << 16); lv.y = l[2] | (l[3] << 16);
            lv.z = l[4] | (l[5] << 16); lv.w = l[6] | (l[7] << 16);
            const int slot = koct * 128 + (row ^ koct);   // swizzled uint4 slot
            ((uint4*)Xhi)[slot] = hv;
            ((uint4*)Xlo)[slot] = lv;
        }
    }
    __syncthreads();   // compiler drains vmcnt(0)+lgkmcnt(0) before s_barrier

    // ---- Compute: wave (wr,wc) owns 64x64; 4x4 tiles of 16x16, K=128.
    const int wr  = (wv >> 1) * 64;
    const int wc  = (wv & 1) * 64;
    const int l16 = lane & 15;
    const int q   = lane >> 4;

    f32x4 acc[4][4];
#pragma unroll
    for (int rt = 0; rt < 4; ++rt)
#pragma unroll
        for (int ct = 0; ct < 4; ++ct) acc[rt][ct] = (f32x4)(0.0f);

#pragma unroll
    for (int kk = 0; kk < 4; ++kk) {
        const int fb = kk * 4 + q;               // k-octet 0..15
        bfrag ah[4], al[4], bh[4], bl[4];
#pragma unroll
        for (int rt = 0; rt < 4; ++rt) {
            const int row = wr + rt * 16 + l16;
            const int off = (fb * 128 + (row ^ fb)) * 8;     // shorts
            ah[rt] = *(const bfrag*)&Xhi[off];
            al[rt] = *(const bfrag*)&Xlo[off];
        }
#pragma unroll
        for (int ct = 0; ct < 4; ++ct) {
            const int off = (fb * 128 + wc + ct * 16 + l16) * 8;
            bh[ct] = *(const bfrag*)&Wl[off];
            bl[ct] = *(const bfrag*)&Wl[16384 + off];
        }
#pragma unroll
        for (int rt = 0; rt < 4; ++rt)
#pragma unroll
            for (int ct = 0; ct < 4; ++ct) {
                acc[rt][ct] = __builtin_amdgcn_mfma_f32_16x16x32_bf16(
                    ah[rt], bh[ct], acc[rt][ct], 0, 0, 0);
                acc[rt][ct] = __builtin_amdgcn_mfma_f32_16x16x32_bf16(
                    ah[rt], bl[ct], acc[rt][ct], 0, 0, 0);
                acc[rt][ct] = __builtin_amdgcn_mfma_f32_16x16x32_bf16(
                    al[rt], bh[ct], acc[rt][ct], 0, 0, 0);
            }
    }

    // ---- Store. D elem r of a tile: row = (lane>>4)*4 + r, col = lane&15.
#pragma unroll
    for (int rt = 0; rt < 4; ++rt) {
#pragma unroll
        for (int r = 0; r < 4; ++r) {
            const int row = wr + rt * 16 + q * 4 + r;
            if (row0 + row < nrows) {
                float* dst = Ho + (size_t)(row0 + row) * UNITS + wc + l16;
#pragma unroll
                for (int ct = 0; ct < 4; ++ct) dst[ct * 16] = acc[rt][ct][r];
            }
        }
    }
}

// ---------------------------------------------------------------------------
// CSR build: hist -> scanA -> scanC2 (incl. chunk-offset scan) -> fill
// ---------------------------------------------------------------------------
__global__ __launch_bounds__(256) void hist_k(
    const int* __restrict__ c_dst, const int* __restrict__ w_dst,
    int* __restrict__ count)
{
    int i = blockIdx.x * 256 + threadIdx.x;
    if (i >= NE2) return;
    int d = (i < NEDGE) ? c_dst[i] : w_dst[i - NEDGE];
    atomicAdd(&count[d], 1);
}

// per-1024-chunk sums
__global__ __launch_bounds__(256) void scanA(
    const int* __restrict__ count, int* __restrict__ csum)
{
    __shared__ int red[256];
    const int c = blockIdx.x, t = threadIdx.x;
    const int base = c * CHUNK + t * 4;
    int s = 0;
#pragma unroll
    for (int r = 0; r < 4; ++r)
        if (base + r < NP) s += count[base + r];
    red[t] = s; __syncthreads();
#pragma unroll
    for (int off = 128; off > 0; off >>= 1) {
        if (t < off) red[t] += red[t + off];
        __syncthreads();
    }
    if (t == 0) csum[c] = red[0];
}

// chunk-offset scan (inlined old scanB) + in-chunk exclusive scan -> cursor
__global__ __launch_bounds__(256) void scanC2(
    const int* __restrict__ count, const int* __restrict__ csum,
    int* __restrict__ cursor)
{
    __shared__ int bs[128];
    __shared__ int ts[256];
    const int c = blockIdx.x, t = threadIdx.x;

    // local scan of the 98 chunk sums (every block redoes this tiny scan)
    if (t < 128) bs[t] = (t < NCHUNK) ? csum[t] : 0;
    __syncthreads();
    for (int off = 1; off < 128; off <<= 1) {
        int x = 0;
        if (t < 128 && t >= off) x = bs[t - off];
        __syncthreads();
        if (t < 128) bs[t] += x;
        __syncthreads();
    }
    const int coffc = (c == 0) ? 0 : bs[c - 1];

    // in-chunk exclusive scan (4 counts per thread)
    const int base = c * CHUNK + t * 4;
    int v0 = 0, v1 = 0, v2 = 0, v3 = 0;
    if (base + 0 < NP) v0 = count[base + 0];
    if (base + 1 < NP) v1 = count[base + 1];
    if (base + 2 < NP) v2 = count[base + 2];
    if (base + 3 < NP) v3 = count[base + 3];
    const int s = v0 + v1 + v2 + v3;
    ts[t] = s; __syncthreads();
    for (int off = 1; off < 256; off <<= 1) {
        int x = (t >= off) ? ts[t - off] : 0;
        __syncthreads();
        ts[t] += x;
        __syncthreads();
    }
    int excl = ts[t] - s + coffc;
    if (base + 0 < NP) cursor[base + 0] = excl;
    if (base + 1 < NP) cursor[base + 1] = excl + v0;
    if (base + 2 < NP) cursor[base + 2] = excl + v0 + v1;
    if (base + 3 < NP) cursor[base + 3] = excl + v0 + v1 + v2;
}

// scatter edge payloads (sender H-row id); cursor[n] advances to segment end
__global__ __launch_bounds__(256) void fill_k(
    const int* __restrict__ c_src, const int* __restrict__ c_dst,
    const int* __restrict__ w_src, const int* __restrict__ w_dst,
    int* __restrict__ cursor, int* __restrict__ eidx)
{
    int i = blockIdx.x * 256 + threadIdx.x;
    if (i >= NE2) return;
    int d, val;
    if (i < NEDGE) { d = c_dst[i];         val = c_src[i]; }
    else           { int j = i - NEDGE; d = w_dst[j]; val = NP + w_src[j]; }
    int pos = atomicAdd(&cursor[d], 1);
    eidx[pos] = val;
}

// ---------------------------------------------------------------------------
// Atomic-free gather + mean + bias + relu. Self term pre-written into out[].
// 8 nodes/block, 32 lanes/node. Unrolled x2: two independent float4 loads in
// flight per lane (MLP) — mean degree ~10 edges/node.
// ---------------------------------------------------------------------------
__global__ __launch_bounds__(256) void gather_fused(
    const float* __restrict__ H, const int* __restrict__ eidx,
    const int* __restrict__ cursor, const float* __restrict__ bias,
    float* __restrict__ out)
{
    const int tid = threadIdx.x;
    const int g = tid >> 5, l = tid & 31;
    const int n = blockIdx.x * 8 + g;      // NP % 8 == 0, no tail

    float4 acc = ((const float4*)out)[(size_t)n * 32 + l];
    float4 acc2; acc2.x = acc2.y = acc2.z = acc2.w = 0.0f;

    const int start = (n == 0) ? 0 : cursor[n - 1];
    const int end   = cursor[n];
    const float4* H4 = (const float4*)H;

    int j = start;
    for (; j + 2 <= end; j += 2) {
        const int e0 = eidx[j];
        const int e1 = eidx[j + 1];
        const float4 v0 = H4[(size_t)e0 * 32 + l];
        const float4 v1 = H4[(size_t)e1 * 32 + l];
        acc.x  += v0.x; acc.y  += v0.y; acc.z  += v0.z; acc.w  += v0.w;
        acc2.x += v1.x; acc2.y += v1.y; acc2.z += v1.z; acc2.w += v1.w;
    }
    if (j < end) {
        const float4 v = H4[(size_t)eidx[j] * 32 + l];
        acc.x += v.x; acc.y += v.y; acc.z += v.z; acc.w += v.w;
    }
    acc.x += acc2.x; acc.y += acc2.y; acc.z += acc2.z; acc.w += acc2.w;

    const float inv = 1.0f / (float)(end - start + 1);      // +1 self-loop
    const float4 b = ((const float4*)bias)[l];
    float4 o;
    o.x = fmaxf(fmaf(acc.x, inv, b.x), 0.0f);
    o.y = fmaxf(fmaf(acc.y, inv, b.y), 0.0f);
    o.z = fmaxf(fmaf(acc.z, inv, b.z), 0.0f);
    o.w = fmaxf(fmaf(acc.w, inv, b.w), 0.0f);
    ((float4*)out)[(size_t)n * 32 + l] = o;
}

// ---------------------------------------------------------------------------
extern "C" void kernel_launch(void* const* d_in, const int* in_sizes, int n_in,
                              void* d_out, int out_size, void* d_ws, size_t ws_size,
                              hipStream_t stream)
{
    const float* x_paper    = (const float*)d_in[0];
    const float* x_author   = (const float*)d_in[1];
    const float* W_cites    = (const float*)d_in[2];
    const float* W_writes   = (const float*)d_in[3];
    const float* W_self     = (const float*)d_in[4];
    const float* bias       = (const float*)d_in[5];
    const int*   cites_src  = (const int*)d_in[6];
    const int*   cites_dst  = (const int*)d_in[7];
    const int*   writes_src = (const int*)d_in[8];
    const int*   writes_dst = (const int*)d_in[9];
    float* out = (float*)d_out;

    // Workspace (~81.8 MB, well under the 128.4 MB proven in round 3):
    //   H      : 150000*128 f32 = 76.8 MB
    //   eidx   : 1M int  = 4.0 MB
    //   count/cursor : NP int each; csum ~0.4 KB; Wpk 192 KB
    char* ws = (char*)d_ws;
    float*          H      = (float*)(ws);
    int*            eidx   = (int*)(ws + 76800000);
    int*            count  = (int*)(ws + 80800000);
    int*            cursor = (int*)(ws + 81200000);
    int*            csum   = (int*)(ws + 81600000);
    unsigned short* Wpk    = (unsigned short*)(ws + 81601024);

    // W pre-pack (3 blocks) + count zero (391 blocks).
    wpack_zero<<<3 + (NP + 255) / 256, 256, 0, stream>>>(
        W_cites, W_writes, W_self, Wpk, count);

    // All three transforms via bf16-split MFMA (self -> out).
    mfma_gemm_all<<<2 * GPB + GAB, 256, 0, stream>>>(
        x_paper, x_author, Wpk, H, out);

    // CSR build over both edge sets combined.
    hist_k<<<(NE2 + 255) / 256, 256, 0, stream>>>(cites_dst, writes_dst, count);
    scanA<<<NCHUNK, 256, 0, stream>>>(count, csum);
    scanC2<<<NCHUNK, 256, 0, stream>>>(count, csum, cursor);
    fill_k<<<(NE2 + 255) / 256, 256, 0, stream>>>(
        cites_src, cites_dst, writes_src, writes_dst, cursor, eidx);

    // Atomic-free gather + finalize (reads self term from out, overwrites out).
    gather_fused<<<NP / 8, 256, 0, stream>>>(H, eidx, cursor, bias, out);
}